// Round 7
// baseline (869.921 us; speedup 1.0000x reference)
//
#include <hip/hip_runtime.h>
#include <hip/hip_bf16.h>
#include <stdint.h>

#define HEADS 4
#define SLOPE 0.2f

typedef unsigned short u16;
typedef float f32x4 __attribute__((ext_vector_type(4)));
typedef short s16x8 __attribute__((ext_vector_type(8)));
typedef unsigned short u16x4 __attribute__((ext_vector_type(4)));

__device__ __forceinline__ u16 f2bf(float f) {
    unsigned int u = __float_as_uint(f);
    u = (u + 0x7fffu + ((u >> 16) & 1u)) >> 16;   // round-to-nearest-even
    return (u16)u;
}
__device__ __forceinline__ float bf2f(u16 v) {
    return __uint_as_float(((unsigned int)v) << 16);
}
__device__ __forceinline__ float fin(float x) {
    return (x == x && fabsf(x) < 1e30f) ? x : 0.f;
}

// ---------------------------------------------------------------- fused prep
// zero(deg) + cast inp -> Xb (SPLIT-MAJOR [k/32][n][32]) + transpose W1/W2/W3.
__global__ void prep_kernel(const float* __restrict__ inp, u16* __restrict__ Xb,
                            const float* __restrict__ W1, u16* __restrict__ Wt1,
                            const float* __restrict__ W2, u16* __restrict__ Wt2,
                            const float* __restrict__ W3, u16* __restrict__ Wt3,
                            int* __restrict__ deg, int N) {
    int i = blockIdx.x * blockDim.x + threadIdx.x;
    int castN = N * 128;
    if (i < N) deg[i] = 0;
    i -= N;
    if (i >= 0 && i < castN) {
        int n = i >> 7, k = i & 127;
        Xb[(size_t)(k >> 5) * ((size_t)N * 32) + (size_t)n * 32 + (k & 31)] = f2bf(fin(inp[i]));
        return;
    }
    i -= castN;
    if (i >= 0 && i < 128 * 256) {          // W1 [128 x 256] -> Wt1 [256 x 128]
        int k = i >> 8, m = i & 255;
        Wt1[m * 128 + k] = f2bf(fin(W1[i]));
        return;
    }
    i -= 128 * 256;
    if (i >= 0 && i < 256 * 256) {
        int k = i >> 8, m = i & 255;
        Wt2[m * 256 + k] = f2bf(fin(W2[i]));
        return;
    }
    i -= 256 * 256;
    if (i >= 0 && i < 256 * 256) {
        int k = i >> 8, m = i & 255;
        Wt3[m * 256 + k] = f2bf(fin(W3[i]));
    }
}

// ---------------------------------------------------------------- CSR build
__global__ void count_kernel(const int* __restrict__ dst, int* __restrict__ deg,
                             int E, int N) {
    int i = blockIdx.x * blockDim.x + threadIdx.x;
    if (i < E + N) {
        int d = (i < E) ? dst[i] : (i - E);   // self-loops appended
        d = ((unsigned)d < (unsigned)N) ? d : 0;
        atomicAdd(&deg[d], 1);
    }
}

// Single-dispatch scan: block b redundantly sums deg[0 .. b*1024) (cheap O(B^2)),
// then scans its own 1024-element chunk. Replaces 3-kernel hierarchical scan.
__global__ __launch_bounds__(256) void scan_kernel(const int* __restrict__ deg,
                                                   int* __restrict__ rowstart,
                                                   int* __restrict__ cursor, int N) {
    __shared__ int wsum[4];
    __shared__ int sm[256];
    int b = blockIdx.x, tid = threadIdx.x;
    int start = b * 1024;
    int pre = 0;
    for (int i = tid; i < start; i += 256) pre += deg[i];   // start < N always
    #pragma unroll
    for (int off = 1; off <= 32; off <<= 1) pre += __shfl_xor(pre, off);
    if ((tid & 63) == 0) wsum[tid >> 6] = pre;
    __syncthreads();
    int block_pre = wsum[0] + wsum[1] + wsum[2] + wsum[3];

    int base = start + tid * 4;
    int v[4]; int s = 0;
    #pragma unroll
    for (int j = 0; j < 4; j++) { int i = base + j; v[j] = (i < N) ? deg[i] : 0; s += v[j]; }
    sm[tid] = s;
    __syncthreads();
    for (int off = 1; off < 256; off <<= 1) {
        int t = (tid >= off) ? sm[tid - off] : 0;
        __syncthreads();
        sm[tid] += t;
        __syncthreads();
    }
    int run = block_pre + sm[tid] - s;
    #pragma unroll
    for (int j = 0; j < 4; j++) {
        int i = base + j;
        if (i < N) { rowstart[i] = run; cursor[i] = run; run += v[j]; }
    }
    if (b == gridDim.x - 1 && tid == 255) rowstart[N] = block_pre + sm[255];
}

__global__ void scatter_kernel(const int* __restrict__ src, const int* __restrict__ dst,
                               int* __restrict__ cursor, int* __restrict__ csr,
                               int E, int N) {
    int i = blockIdx.x * blockDim.x + threadIdx.x;
    if (i < E + N) {
        int s, d;
        if (i < E) { s = src[i]; d = dst[i]; }
        else       { s = i - E; d = i - E; }
        s = ((unsigned)s < (unsigned)N) ? s : 0;
        d = ((unsigned)d < (unsigned)N) ? d : 0;
        int pos = atomicAdd(&cursor[d], 1);
        if ((unsigned)pos < (unsigned)(E + N)) csr[pos] = s;
    }
}

// ---------------------------------------------------------------- GEMM (bf16 MFMA)
// A is SPLIT-MAJOR: X[s][n][32] with s = k/32 (identity K-permutation, Wt flat).
// Hout flat [N x 256] bf16. 4 waves/block, block tile 64x256, wave tile 32x128.
__global__ __launch_bounds__(256) void gemm_kernel(
        const u16* __restrict__ X, const u16* __restrict__ Wt,
        u16* __restrict__ Hout, int N, int K) {
    int wv = threadIdx.x >> 6, lane = threadIdx.x & 63;
    int quad = lane >> 4, l16 = lane & 15;
    int m0 = (blockIdx.x * 2 + (wv & 1)) * 32;
    int n0 = (wv >> 1) * 128;
    size_t chunk = (size_t)N * 32;

    f32x4 acc[2][8];
    #pragma unroll
    for (int r = 0; r < 2; r++)
        #pragma unroll
        for (int c = 0; c < 8; c++) acc[r][c] = (f32x4){0.f, 0.f, 0.f, 0.f};

    for (int k0 = 0; k0 < K; k0 += 32) {
        const u16* Ablk = X + (size_t)(k0 >> 5) * chunk + quad * 8;
        s16x8 a[2], b[8];
        #pragma unroll
        for (int r = 0; r < 2; r++) {
            int row = m0 + r * 16 + l16;
            row = row < N ? row : N - 1;
            a[r] = *(const s16x8*)(Ablk + (size_t)row * 32);
        }
        #pragma unroll
        for (int c = 0; c < 8; c++) {
            int n = n0 + c * 16 + l16;
            b[c] = *(const s16x8*)(Wt + (size_t)n * K + k0 + quad * 8);
        }
        #pragma unroll
        for (int r = 0; r < 2; r++)
            #pragma unroll
            for (int c = 0; c < 8; c++)
                acc[r][c] = __builtin_amdgcn_mfma_f32_16x16x32_bf16(a[r], b[c], acc[r][c], 0, 0, 0);
    }

    // C/D layout: col = lane&15, row = quad*4 + reg
    #pragma unroll
    for (int r = 0; r < 2; r++) {
        int rowb = m0 + r * 16 + quad * 4;
        #pragma unroll
        for (int c = 0; c < 8; c++) {
            int col = n0 + c * 16 + l16;
            #pragma unroll
            for (int j = 0; j < 4; j++) {
                int row = rowb + j;
                if (row < N) Hout[(size_t)row * 256 + col] = f2bf(acc[r][c][j]);
            }
        }
    }
}

// ---------------------------------------------------------------- per-node logits
__global__ __launch_bounds__(256) void alphas_kernel(
        const u16* __restrict__ Hb, const float* __restrict__ att_src,
        const float* __restrict__ att_dst, float* __restrict__ as_out,
        float* __restrict__ ad_out, int N) {
    int wv = threadIdx.x >> 6, lane = threadIdx.x & 63;
    int n = blockIdx.x * 4 + wv;
    if (n >= N) return;
    u16x4 hv = *(const u16x4*)(Hb + (size_t)n * 256 + lane * 4);
    f32x4 sv = *(const f32x4*)(att_src + lane * 4);
    f32x4 dv = *(const f32x4*)(att_dst + lane * 4);
    float ps = 0.f, pd = 0.f;
    #pragma unroll
    for (int j = 0; j < 4; j++) {
        float h = bf2f(hv[j]);
        ps += h * fin(sv[j]);
        pd += h * fin(dv[j]);
    }
    #pragma unroll
    for (int off = 1; off <= 8; off <<= 1) {
        ps += __shfl_xor(ps, off);
        pd += __shfl_xor(pd, off);
    }
    if ((lane & 15) == 0) {
        int head = lane >> 4;
        as_out[n * 4 + head] = ps;
        ad_out[n * 4 + head] = pd;
    }
}

// ---------------------------------------------------------------- fused softmax-gather v3
// 8-way CHANNEL SPLIT, XCD-affine: split = blockIdx & 7 (round-robin blockIdx->XCD
// means each XCD gathers only its 3.2 MB slice of Hb -> L2-resident).
// Wave per (node, split): 8 edge-slots x 8 lanes; lane covers 4 channels (8 B load);
// slice = channels [32s, 32s+32), head h = s>>1. Inline max-free softmax (clamp 80).
// Intermediate out: SPLIT-MAJOR bf16 Xb[s][n][32] (no cross-XCD false sharing);
// final out: flat fp32 (128 B/wave, full lines).
__global__ __launch_bounds__(256) void gather_kernel(
        const u16* __restrict__ Hb, const float* __restrict__ asrc,
        const float* __restrict__ adst, const int* __restrict__ rowstart,
        const int* __restrict__ csr, const float* __restrict__ bias,
        u16* __restrict__ outb, float* __restrict__ outf, int write_f32,
        int N, int Etot) {
    int wv = threadIdx.x >> 6, lane = threadIdx.x & 63;
    int split = blockIdx.x & 7;
    int n = (blockIdx.x >> 3) * 4 + wv;
    if (n >= N) return;
    int slot = lane >> 3, cl = lane & 7;
    int h = split >> 1;
    int c0 = split * 32 + cl * 4;           // this lane's 4 original channels

    int i0 = rowstart[n], i1 = rowstart[n + 1];
    i0 = min(max(i0, 0), Etot);
    i1 = min(max(i1, i0), Etot);

    float adh = adst[n * 4 + h];
    float acc[4] = {0.f, 0.f, 0.f, 0.f};
    float ws = 0.f;

    for (int i = i0 + slot; i < i1; i += 8) {
        int s = csr[i];
        s = ((unsigned)s < (unsigned)N) ? s : 0;
        float e = asrc[s * 4 + h] + adh;
        u16x4 hv = *(const u16x4*)(Hb + (size_t)s * 256 + c0);
        e = e > 0.f ? e : SLOPE * e;        // leaky_relu
        float w = __expf(fminf(e, 80.f));
        ws += w;
        #pragma unroll
        for (int j = 0; j < 4; j++) acc[j] += w * bf2f(hv[j]);
    }

    // reduce across the 8 edge-slots (lanes cl, cl+8, ..., cl+56)
    #pragma unroll
    for (int off = 8; off <= 32; off <<= 1) {
        ws += __shfl_xor(ws, off);
        #pragma unroll
        for (int j = 0; j < 4; j++) acc[j] += __shfl_xor(acc[j], off);
    }

    if (slot == 0) {                        // lanes 0..7 write the slice
        float invh = (ws > 0.f) ? 1.f / ws : 0.f;
        f32x4 bv = *(const f32x4*)(bias + c0);
        float o[4];
        #pragma unroll
        for (int j = 0; j < 4; j++) {
            float v = acc[j] * invh + fin(bv[j]);
            o[j] = v > 0.f ? v : (__expf(v) - 1.f);   // ELU
        }
        if (write_f32) {
            f32x4 ov = {o[0], o[1], o[2], o[3]};
            *(f32x4*)(outf + (size_t)n * 256 + c0) = ov;
        } else {
            u16x4 ob;
            #pragma unroll
            for (int j = 0; j < 4; j++) ob[j] = f2bf(o[j]);
            *(u16x4*)(outb + (size_t)split * ((size_t)N * 32) + (size_t)n * 32 + cl * 4) = ob;
        }
    }
}

// ---------------------------------------------------------------- launch
extern "C" void kernel_launch(void* const* d_in, const int* in_sizes, int n_in,
                              void* d_out, int out_size, void* d_ws, size_t ws_size,
                              hipStream_t stream) {
    const float* inp  = (const float*)d_in[0];
    const int*   ei   = (const int*)d_in[1];
    const float* W1   = (const float*)d_in[2];
    const float* at_s1= (const float*)d_in[3];
    const float* at_d1= (const float*)d_in[4];
    const float* b1   = (const float*)d_in[5];
    const float* W2   = (const float*)d_in[6];
    const float* at_s2= (const float*)d_in[7];
    const float* at_d2= (const float*)d_in[8];
    const float* b2   = (const float*)d_in[9];
    const float* W3   = (const float*)d_in[10];
    const float* at_s3= (const float*)d_in[11];
    const float* at_d3= (const float*)d_in[12];
    const float* b3   = (const float*)d_in[13];

    const int N = in_sizes[0] / 128;   // 50000
    const int E = in_sizes[1] / 2;     // 800000
    const int Etot = E + N;
    const int* esrc = ei;
    const int* edst = ei + E;

    char* p = (char*)d_ws;
    auto alloc = [&](size_t b) -> void* {
        void* q = (void*)p;
        p += (b + 255) & ~(size_t)255;
        return q;
    };
    u16*   Xb       = (u16*)alloc((size_t)N * 256 * 2);   // split-major [8][N][32]
    u16*   Hb       = (u16*)alloc((size_t)N * 256 * 2);   // flat [N][256]
    u16*   Wt1      = (u16*)alloc((size_t)128 * 256 * 2);
    u16*   Wt2      = (u16*)alloc((size_t)256 * 256 * 2);
    u16*   Wt3      = (u16*)alloc((size_t)256 * 256 * 2);
    float* asb      = (float*)alloc((size_t)N * 4 * 4);
    float* adb      = (float*)alloc((size_t)N * 4 * 4);
    int*   deg      = (int*)alloc((size_t)N * 4);
    int*   rowstart = (int*)alloc((size_t)(N + 1) * 4);
    int*   cursor   = (int*)alloc((size_t)N * 4);
    int*   csr      = (int*)alloc((size_t)Etot * 4);
    float* outf     = (float*)d_out;

    const int SB = (N + 1023) / 1024;                        // 49 scan blocks
    const int prep_total = N + N * 128 + 128 * 256 + 2 * 256 * 256;

    prep_kernel<<<(prep_total + 255) / 256, 256, 0, stream>>>(
        inp, Xb, W1, Wt1, W2, Wt2, W3, Wt3, deg, N);
    count_kernel<<<(Etot + 255) / 256, 256, 0, stream>>>(edst, deg, E, N);
    scan_kernel<<<SB, 256, 0, stream>>>(deg, rowstart, cursor, N);
    scatter_kernel<<<(Etot + 255) / 256, 256, 0, stream>>>(esrc, edst, cursor, csr, E, N);

    const int gemm_grid = (N + 63) / 64;
    const int node_grid = (N + 3) / 4;
    const int gath_grid = ((N + 3) / 4) * 8;   // x8 channel splits

    // layer 1 (K=128)
    gemm_kernel<<<gemm_grid, 256, 0, stream>>>(Xb, Wt1, Hb, N, 128);
    alphas_kernel<<<node_grid, 256, 0, stream>>>(Hb, at_s1, at_d1, asb, adb, N);
    gather_kernel<<<gath_grid, 256, 0, stream>>>(Hb, asb, adb, rowstart, csr, b1,
                                                 Xb, outf, 0, N, Etot);
    // layer 2 (K=256)
    gemm_kernel<<<gemm_grid, 256, 0, stream>>>(Xb, Wt2, Hb, N, 256);
    alphas_kernel<<<node_grid, 256, 0, stream>>>(Hb, at_s2, at_d2, asb, adb, N);
    gather_kernel<<<gath_grid, 256, 0, stream>>>(Hb, asb, adb, rowstart, csr, b2,
                                                 Xb, outf, 0, N, Etot);
    // layer 3 (K=256) -> fp32 d_out
    gemm_kernel<<<gemm_grid, 256, 0, stream>>>(Xb, Wt3, Hb, N, 256);
    alphas_kernel<<<node_grid, 256, 0, stream>>>(Hb, at_s3, at_d3, asb, adb, N);
    gather_kernel<<<gath_grid, 256, 0, stream>>>(Hb, asb, adb, rowstart, csr, b3,
                                                 Xb, outf, 1, N, Etot);
}

// Round 8
// 541.910 us; speedup vs baseline: 1.6053x; 1.6053x over previous
//
#include <hip/hip_runtime.h>
#include <hip/hip_bf16.h>
#include <stdint.h>

#define HEADS 4
#define SLOPE 0.2f

typedef unsigned short u16;
typedef float f32x4 __attribute__((ext_vector_type(4)));
typedef short s16x8 __attribute__((ext_vector_type(8)));
typedef unsigned short u16x4 __attribute__((ext_vector_type(4)));

__device__ __forceinline__ u16 f2bf(float f) {
    unsigned int u = __float_as_uint(f);
    u = (u + 0x7fffu + ((u >> 16) & 1u)) >> 16;   // round-to-nearest-even
    return (u16)u;
}
__device__ __forceinline__ float bf2f(u16 v) {
    return __uint_as_float(((unsigned int)v) << 16);
}
__device__ __forceinline__ float fin(float x) {
    return (x == x && fabsf(x) < 1e30f) ? x : 0.f;
}

// ---------------------------------------------------------------- fused prep
// zero(deg) + cast inp -> Xb (flat [N][128]) + transpose W1/W2/W3.
__global__ void prep_kernel(const float* __restrict__ inp, u16* __restrict__ Xb,
                            const float* __restrict__ W1, u16* __restrict__ Wt1,
                            const float* __restrict__ W2, u16* __restrict__ Wt2,
                            const float* __restrict__ W3, u16* __restrict__ Wt3,
                            int* __restrict__ deg, int N) {
    int i = blockIdx.x * blockDim.x + threadIdx.x;
    int castN = N * 128;
    if (i < N) deg[i] = 0;
    i -= N;
    if (i >= 0 && i < castN) {
        Xb[i] = f2bf(fin(inp[i]));
        return;
    }
    i -= castN;
    if (i >= 0 && i < 128 * 256) {          // W1 [128 x 256] -> Wt1 [256 x 128]
        int k = i >> 8, m = i & 255;
        Wt1[m * 128 + k] = f2bf(fin(W1[i]));
        return;
    }
    i -= 128 * 256;
    if (i >= 0 && i < 256 * 256) {
        int k = i >> 8, m = i & 255;
        Wt2[m * 256 + k] = f2bf(fin(W2[i]));
        return;
    }
    i -= 256 * 256;
    if (i >= 0 && i < 256 * 256) {
        int k = i >> 8, m = i & 255;
        Wt3[m * 256 + k] = f2bf(fin(W3[i]));
    }
}

// ---------------------------------------------------------------- CSR build
__global__ void count_kernel(const int* __restrict__ dst, int* __restrict__ deg,
                             int E, int N) {
    int i = blockIdx.x * blockDim.x + threadIdx.x;
    if (i < E + N) {
        int d = (i < E) ? dst[i] : (i - E);   // self-loops appended
        d = ((unsigned)d < (unsigned)N) ? d : 0;
        atomicAdd(&deg[d], 1);
    }
}

// Single-dispatch scan: block b redundantly sums deg[0 .. b*1024), then scans
// its own 1024-element chunk (O(B^2) pre-sum is cheap at B=49).
__global__ __launch_bounds__(256) void scan_kernel(const int* __restrict__ deg,
                                                   int* __restrict__ rowstart,
                                                   int* __restrict__ cursor, int N) {
    __shared__ int wsum[4];
    __shared__ int sm[256];
    int b = blockIdx.x, tid = threadIdx.x;
    int start = b * 1024;
    int pre = 0;
    for (int i = tid; i < start; i += 256) pre += deg[i];
    #pragma unroll
    for (int off = 1; off <= 32; off <<= 1) pre += __shfl_xor(pre, off);
    if ((tid & 63) == 0) wsum[tid >> 6] = pre;
    __syncthreads();
    int block_pre = wsum[0] + wsum[1] + wsum[2] + wsum[3];

    int base = start + tid * 4;
    int v[4]; int s = 0;
    #pragma unroll
    for (int j = 0; j < 4; j++) { int i = base + j; v[j] = (i < N) ? deg[i] : 0; s += v[j]; }
    sm[tid] = s;
    __syncthreads();
    for (int off = 1; off < 256; off <<= 1) {
        int t = (tid >= off) ? sm[tid - off] : 0;
        __syncthreads();
        sm[tid] += t;
        __syncthreads();
    }
    int run = block_pre + sm[tid] - s;
    #pragma unroll
    for (int j = 0; j < 4; j++) {
        int i = base + j;
        if (i < N) { rowstart[i] = run; cursor[i] = run; run += v[j]; }
    }
    if (b == gridDim.x - 1 && tid == 255) rowstart[N] = block_pre + sm[255];
}

__global__ void scatter_kernel(const int* __restrict__ src, const int* __restrict__ dst,
                               int* __restrict__ cursor, int* __restrict__ csr,
                               int E, int N) {
    int i = blockIdx.x * blockDim.x + threadIdx.x;
    if (i < E + N) {
        int s, d;
        if (i < E) { s = src[i]; d = dst[i]; }
        else       { s = i - E; d = i - E; }
        s = ((unsigned)s < (unsigned)N) ? s : 0;
        d = ((unsigned)d < (unsigned)N) ? d : 0;
        int pos = atomicAdd(&cursor[d], 1);
        if ((unsigned)pos < (unsigned)(E + N)) csr[pos] = s;
    }
}

// ---------------------------------------------------------------- GEMM + fused alphas
// Hb[N x 256] = Xb[N x K] @ W; plus as/ad[n][h] = sum_c Hb[n][h*64+c]*att_{src,dst}[h*64+c]
// computed from the accumulators before the bf16 store (saves a full Hb re-read).
// Block tile 64 rows x 256 cols; wave tile 32x128. A wave's 128-col half maps to
// exactly 2 heads (head0 = n0>>6), so the alpha reduction is l16-shuffle only —
// no cross-wave reduction, no atomics.
__global__ __launch_bounds__(256) void gemm_kernel(
        const u16* __restrict__ X, const u16* __restrict__ Wt,
        u16* __restrict__ Hout, const float* __restrict__ att_src,
        const float* __restrict__ att_dst, float* __restrict__ as_out,
        float* __restrict__ ad_out, int N, int K) {
    int wv = threadIdx.x >> 6, lane = threadIdx.x & 63;
    int quad = lane >> 4, l16 = lane & 15;
    int m0 = (blockIdx.x * 2 + (wv & 1)) * 32;
    int n0 = (wv >> 1) * 128;

    f32x4 acc[2][8];
    #pragma unroll
    for (int r = 0; r < 2; r++)
        #pragma unroll
        for (int c = 0; c < 8; c++) acc[r][c] = (f32x4){0.f, 0.f, 0.f, 0.f};

    for (int k0 = 0; k0 < K; k0 += 32) {
        s16x8 a[2], b[8];
        #pragma unroll
        for (int r = 0; r < 2; r++) {
            int row = m0 + r * 16 + l16;
            row = row < N ? row : N - 1;
            a[r] = *(const s16x8*)(X + (size_t)row * K + k0 + quad * 8);
        }
        #pragma unroll
        for (int c = 0; c < 8; c++) {
            int n = n0 + c * 16 + l16;
            b[c] = *(const s16x8*)(Wt + (size_t)n * K + k0 + quad * 8);
        }
        #pragma unroll
        for (int r = 0; r < 2; r++)
            #pragma unroll
            for (int c = 0; c < 8; c++)
                acc[r][c] = __builtin_amdgcn_mfma_f32_16x16x32_bf16(a[r], b[c], acc[r][c], 0, 0, 0);
    }

    // Epilogue: store bf16 H and accumulate alpha partials.
    // C/D layout: col = n0 + c*16 + l16, row = m0 + r*16 + quad*4 + j.
    int head0 = n0 >> 6;
    float aps[2][4][2], apd[2][4][2];   // [r][j][hh]
    #pragma unroll
    for (int r = 0; r < 2; r++)
        #pragma unroll
        for (int j = 0; j < 4; j++)
            aps[r][j][0] = aps[r][j][1] = apd[r][j][0] = apd[r][j][1] = 0.f;

    #pragma unroll
    for (int r = 0; r < 2; r++) {
        int rowb = m0 + r * 16 + quad * 4;
        #pragma unroll
        for (int c = 0; c < 8; c++) {
            int col = n0 + c * 16 + l16;
            float av = fin(att_src[col]);
            float dv = fin(att_dst[col]);
            int hh = c >> 2;
            #pragma unroll
            for (int j = 0; j < 4; j++) {
                int row = rowb + j;
                float v = acc[r][c][j];
                aps[r][j][hh] += v * av;
                apd[r][j][hh] += v * dv;
                if (row < N) Hout[(size_t)row * 256 + col] = f2bf(v);
            }
        }
    }
    // reduce over the 16 l16 lanes (columns within a head-half)
    #pragma unroll
    for (int off = 1; off <= 8; off <<= 1) {
        #pragma unroll
        for (int r = 0; r < 2; r++)
            #pragma unroll
            for (int j = 0; j < 4; j++) {
                aps[r][j][0] += __shfl_xor(aps[r][j][0], off);
                aps[r][j][1] += __shfl_xor(aps[r][j][1], off);
                apd[r][j][0] += __shfl_xor(apd[r][j][0], off);
                apd[r][j][1] += __shfl_xor(apd[r][j][1], off);
            }
    }
    if (l16 == 0) {
        #pragma unroll
        for (int r = 0; r < 2; r++) {
            int rowb = m0 + r * 16 + quad * 4;
            #pragma unroll
            for (int j = 0; j < 4; j++) {
                int row = rowb + j;
                if (row < N) {
                    #pragma unroll
                    for (int hh = 0; hh < 2; hh++) {
                        as_out[row * 4 + head0 + hh] = aps[r][j][hh];
                        ad_out[row * 4 + head0 + hh] = apd[r][j][hh];
                    }
                }
            }
        }
    }
}

// ---------------------------------------------------------------- fused softmax-gather
// (R6 version — measured 69.5 us.) Wave per node; 2 half-wave edge slots; lane
// covers 8 channels (16 B load) of head h = (lane&31)>>3. Inline max-free softmax
// (clamp 80). Edge loop unrolled x2 per slot -> 4 independent row loads in flight.
__global__ __launch_bounds__(256) void gather_kernel(
        const u16* __restrict__ Hb, const float* __restrict__ asrc,
        const float* __restrict__ adst, const int* __restrict__ rowstart,
        const int* __restrict__ csr, const float* __restrict__ bias,
        u16* __restrict__ outb, float* __restrict__ outf, int write_f32,
        int N, int Etot) {
    int wv = threadIdx.x >> 6, lane = threadIdx.x & 63;
    int n = blockIdx.x * 4 + wv;
    if (n >= N) return;
    int es = lane >> 5, c = lane & 31;    // edge slot; 8-channel group
    int h = c >> 3;
    int i0 = rowstart[n], i1 = rowstart[n + 1];
    i0 = min(max(i0, 0), Etot);
    i1 = min(max(i1, i0), Etot);

    float adh = adst[n * 4 + h];
    float acc[8];
    float ws = 0.f;
    #pragma unroll
    for (int j = 0; j < 8; j++) acc[j] = 0.f;

    int i = i0 + es;
    for (; i + 2 < i1; i += 4) {
        int sA = csr[i], sB = csr[i + 2];
        sA = ((unsigned)sA < (unsigned)N) ? sA : 0;
        sB = ((unsigned)sB < (unsigned)N) ? sB : 0;
        float eA = asrc[sA * 4 + h] + adh;
        float eB = asrc[sB * 4 + h] + adh;
        s16x8 hvA = *(const s16x8*)(Hb + (size_t)sA * 256 + c * 8);
        s16x8 hvB = *(const s16x8*)(Hb + (size_t)sB * 256 + c * 8);
        eA = eA > 0.f ? eA : SLOPE * eA;
        eB = eB > 0.f ? eB : SLOPE * eB;
        float wA = __expf(fminf(eA, 80.f));
        float wB = __expf(fminf(eB, 80.f));
        ws += wA + wB;
        #pragma unroll
        for (int j = 0; j < 8; j++)
            acc[j] += wA * bf2f((u16)hvA[j]) + wB * bf2f((u16)hvB[j]);
    }
    if (i < i1) {
        int s = csr[i];
        s = ((unsigned)s < (unsigned)N) ? s : 0;
        float e = asrc[s * 4 + h] + adh;
        s16x8 hv = *(const s16x8*)(Hb + (size_t)s * 256 + c * 8);
        e = e > 0.f ? e : SLOPE * e;
        float w = __expf(fminf(e, 80.f));
        ws += w;
        #pragma unroll
        for (int j = 0; j < 8; j++) acc[j] += w * bf2f((u16)hv[j]);
    }

    ws += __shfl_xor(ws, 32);
    #pragma unroll
    for (int j = 0; j < 8; j++) acc[j] += __shfl_xor(acc[j], 32);

    if (es == 0) {
        float invh = (ws > 0.f) ? 1.f / ws : 0.f;
        f32x4 blo = *(const f32x4*)(bias + c * 8);
        f32x4 bhi = *(const f32x4*)(bias + c * 8 + 4);
        size_t base = (size_t)n * 256 + c * 8;
        float o[8];
        #pragma unroll
        for (int j = 0; j < 8; j++) {
            float v = acc[j] * invh + fin(j < 4 ? blo[j] : bhi[j - 4]);
            o[j] = v > 0.f ? v : (__expf(v) - 1.f);   // ELU
        }
        if (write_f32) {
            f32x4 lo = {o[0], o[1], o[2], o[3]}, hi = {o[4], o[5], o[6], o[7]};
            *(f32x4*)(outf + base) = lo;
            *(f32x4*)(outf + base + 4) = hi;
        } else {
            s16x8 ob;
            #pragma unroll
            for (int j = 0; j < 8; j++) ob[j] = (short)f2bf(o[j]);
            *(s16x8*)(outb + base) = ob;
        }
    }
}

// ---------------------------------------------------------------- launch
extern "C" void kernel_launch(void* const* d_in, const int* in_sizes, int n_in,
                              void* d_out, int out_size, void* d_ws, size_t ws_size,
                              hipStream_t stream) {
    const float* inp  = (const float*)d_in[0];
    const int*   ei   = (const int*)d_in[1];
    const float* W1   = (const float*)d_in[2];
    const float* at_s1= (const float*)d_in[3];
    const float* at_d1= (const float*)d_in[4];
    const float* b1   = (const float*)d_in[5];
    const float* W2   = (const float*)d_in[6];
    const float* at_s2= (const float*)d_in[7];
    const float* at_d2= (const float*)d_in[8];
    const float* b2   = (const float*)d_in[9];
    const float* W3   = (const float*)d_in[10];
    const float* at_s3= (const float*)d_in[11];
    const float* at_d3= (const float*)d_in[12];
    const float* b3   = (const float*)d_in[13];

    const int N = in_sizes[0] / 128;   // 50000
    const int E = in_sizes[1] / 2;     // 800000
    const int Etot = E + N;
    const int* esrc = ei;
    const int* edst = ei + E;

    char* p = (char*)d_ws;
    auto alloc = [&](size_t b) -> void* {
        void* q = (void*)p;
        p += (b + 255) & ~(size_t)255;
        return q;
    };
    u16*   Xb       = (u16*)alloc((size_t)N * 256 * 2);
    u16*   Hb       = (u16*)alloc((size_t)N * 256 * 2);
    u16*   Wt1      = (u16*)alloc((size_t)128 * 256 * 2);
    u16*   Wt2      = (u16*)alloc((size_t)256 * 256 * 2);
    u16*   Wt3      = (u16*)alloc((size_t)256 * 256 * 2);
    float* asb      = (float*)alloc((size_t)N * 4 * 4);
    float* adb      = (float*)alloc((size_t)N * 4 * 4);
    int*   deg      = (int*)alloc((size_t)N * 4);
    int*   rowstart = (int*)alloc((size_t)(N + 1) * 4);
    int*   cursor   = (int*)alloc((size_t)N * 4);
    int*   csr      = (int*)alloc((size_t)Etot * 4);
    float* outf     = (float*)d_out;

    const int SB = (N + 1023) / 1024;
    const int prep_total = N + N * 128 + 128 * 256 + 2 * 256 * 256;

    prep_kernel<<<(prep_total + 255) / 256, 256, 0, stream>>>(
        inp, Xb, W1, Wt1, W2, Wt2, W3, Wt3, deg, N);
    count_kernel<<<(Etot + 255) / 256, 256, 0, stream>>>(edst, deg, E, N);
    scan_kernel<<<SB, 256, 0, stream>>>(deg, rowstart, cursor, N);
    scatter_kernel<<<(Etot + 255) / 256, 256, 0, stream>>>(esrc, edst, cursor, csr, E, N);

    const int gemm_grid = (N + 63) / 64;
    const int node_grid = (N + 3) / 4;

    // layer 1 (K=128)
    gemm_kernel<<<gemm_grid, 256, 0, stream>>>(Xb, Wt1, Hb, at_s1, at_d1, asb, adb, N, 128);
    gather_kernel<<<node_grid, 256, 0, stream>>>(Hb, asb, adb, rowstart, csr, b1,
                                                 Xb, outf, 0, N, Etot);
    // layer 2 (K=256)
    gemm_kernel<<<gemm_grid, 256, 0, stream>>>(Xb, Wt2, Hb, at_s2, at_d2, asb, adb, N, 256);
    gather_kernel<<<node_grid, 256, 0, stream>>>(Hb, asb, adb, rowstart, csr, b2,
                                                 Xb, outf, 0, N, Etot);
    // layer 3 (K=256) -> fp32 d_out
    gemm_kernel<<<gemm_grid, 256, 0, stream>>>(Xb, Wt3, Hb, at_s3, at_d3, asb, adb, N, 256);
    gather_kernel<<<node_grid, 256, 0, stream>>>(Hb, asb, adb, rowstart, csr, b3,
                                                 Xb, outf, 1, N, Etot);
}